// Round 1
// baseline (590.783 us; speedup 1.0000x reference)
//
#include <hip/hip_runtime.h>
#include <stdint.h>

typedef short bf16x8 __attribute__((ext_vector_type(8)));
typedef float f32x4 __attribute__((ext_vector_type(4)));

__device__ __forceinline__ unsigned short f2b(float f) {
  union { float f; unsigned u; } v; v.f = f;
  unsigned r = v.u + 0x7fffu + ((v.u >> 16) & 1u);
  return (unsigned short)(r >> 16);
}

// ---------------- transpose + convert f32[R][C] -> bf16 out[C][R] ----------------
__global__ __launch_bounds__(256) void tconv(const float* __restrict__ in,
                                             unsigned short* __restrict__ out,
                                             int R, int C) {
  __shared__ float t[32][33];
  int c0 = blockIdx.x * 32, r0 = blockIdx.y * 32;
  int tx = threadIdx.x & 31, ty = threadIdx.x >> 5;  // 32 x 8
  #pragma unroll
  for (int i = 0; i < 32; i += 8) {
    int r = r0 + ty + i, c = c0 + tx;
    t[ty + i][tx] = (r < R && c < C) ? in[(size_t)r * C + c] : 0.f;
  }
  __syncthreads();
  #pragma unroll
  for (int i = 0; i < 32; i += 8) {
    int c = c0 + ty + i, r = r0 + tx;
    if (c < C && r < R) out[(size_t)c * R + r] = f2b(t[tx][ty + i]);
  }
}

// ---------------- generic MFMA GEMM: C = act(A[M,K] @ BT[N,K]^T + bias) ----------------
// A: bf16 row-major (or f32 row-major when AF32), BT: bf16 [N][K] (i.e. B transposed)
// 64x64 tile, 4 waves (2x2), each wave 32x32 via 2x2 mfma_16x16x32 frags, BK=32.
template <int ACT, bool AF32, bool OBF16>
__global__ __launch_bounds__(256) void gemm_k(const void* __restrict__ Ap,
                                              const unsigned short* __restrict__ BT,
                                              const float* __restrict__ bias,
                                              void* __restrict__ Cp,
                                              int M, int N, int K, int ldC) {
  __shared__ unsigned short As[64][40];  // pad to 40 elems (80B rows, 16B aligned)
  __shared__ unsigned short Bs[64][40];
  const int tid = threadIdx.x;
  const int n0 = blockIdx.x * 64;
  const int m0 = blockIdx.y * 64;
  const int wid = tid >> 6, lane = tid & 63;
  const int wm = (wid >> 1) * 32, wn = (wid & 1) * 32;
  const int lr = lane & 15, lk = lane >> 4;
  const int sr = tid >> 2, sc = (tid & 3) * 8;

  f32x4 acc[2][2] = {};

  for (int k0 = 0; k0 < K; k0 += 32) {
    if (AF32) {
      const float* A = (const float*)Ap;
      const float* p = A + (size_t)(m0 + sr) * K + k0 + sc;
      float4 f0 = *(const float4*)p;
      float4 f1 = *(const float4*)(p + 4);
      bf16x8 v;
      v[0] = (short)f2b(f0.x); v[1] = (short)f2b(f0.y);
      v[2] = (short)f2b(f0.z); v[3] = (short)f2b(f0.w);
      v[4] = (short)f2b(f1.x); v[5] = (short)f2b(f1.y);
      v[6] = (short)f2b(f1.z); v[7] = (short)f2b(f1.w);
      *(bf16x8*)&As[sr][sc] = v;
    } else {
      const unsigned short* A = (const unsigned short*)Ap;
      *(bf16x8*)&As[sr][sc] = *(const bf16x8*)(A + (size_t)(m0 + sr) * K + k0 + sc);
    }
    {
      int n = n0 + sr;
      bf16x8 v = {};
      if (n < N) v = *(const bf16x8*)(BT + (size_t)n * K + k0 + sc);
      *(bf16x8*)&Bs[sr][sc] = v;
    }
    __syncthreads();
    bf16x8 af[2], bfr[2];
    #pragma unroll
    for (int mi = 0; mi < 2; mi++) af[mi] = *(const bf16x8*)&As[wm + mi * 16 + lr][lk * 8];
    #pragma unroll
    for (int ni = 0; ni < 2; ni++) bfr[ni] = *(const bf16x8*)&Bs[wn + ni * 16 + lr][lk * 8];
    #pragma unroll
    for (int mi = 0; mi < 2; mi++)
      #pragma unroll
      for (int ni = 0; ni < 2; ni++)
        acc[mi][ni] = __builtin_amdgcn_mfma_f32_16x16x32_bf16(af[mi], bfr[ni], acc[mi][ni], 0, 0, 0);
    __syncthreads();
  }

  #pragma unroll
  for (int mi = 0; mi < 2; mi++)
    #pragma unroll
    for (int ni = 0; ni < 2; ni++) {
      int col = n0 + wn + ni * 16 + lr;
      if (col >= N) continue;
      float bv = bias[col];
      #pragma unroll
      for (int r = 0; r < 4; r++) {
        int row = m0 + wm + mi * 16 + lk * 4 + r;
        float v = acc[mi][ni][r] + bv;
        if (ACT == 1) v = fmaxf(v, 0.f);
        if (OBF16) ((unsigned short*)Cp)[(size_t)row * ldC + col] = f2b(v);
        else       ((float*)Cp)[(size_t)row * ldC + col] = v;
      }
    }
}

// ---------------- fused LSTM scan over 16 steps ----------------
// Each block owns 32 rows; recurrence is per-row independent so no grid sync.
// h_all written in [n][a][128] order (so head-MLP output rows == final z/q/aux rows).
__global__ __launch_bounds__(256) void lstm_k(const float* __restrict__ c0,
                                              const unsigned short* __restrict__ whhT,  // [512][128] bf16
                                              const float* __restrict__ w_ih,           // [16][512]
                                              const float* __restrict__ b_ih,
                                              const float* __restrict__ b_hh,
                                              unsigned short* __restrict__ h_all) {     // [8192][16][128] bf16
  __shared__ float G[32][516];            // gate pre-activations (padded vs bank conflicts)
  __shared__ float cst[32][128];
  __shared__ unsigned short hst[32][136]; // bf16 h tile, 272B row stride (16B aligned)
  const int tid = threadIdx.x, lane = tid & 63, wid = tid >> 6;
  const int r0 = blockIdx.x * 32;
  const int lr = lane & 15, lk = lane >> 4;

  for (int e = tid; e < 32 * 128; e += 256) {
    int r = e >> 7, j = e & 127;
    float c = c0[(size_t)(r0 + r) * 128 + j];
    cst[r][j] = c;
    hst[r][j] = f2b(tanhf(c));
  }
  __syncthreads();

  for (int a = 0; a < 16; a++) {
    // G[:, wid*128 .. +128] = hst @ whhT-slice  (each wave computes one gate block)
    f32x4 acc[2][8] = {};
    #pragma unroll
    for (int ks = 0; ks < 4; ks++) {
      bf16x8 af0 = *(const bf16x8*)&hst[lr][ks * 32 + lk * 8];
      bf16x8 af1 = *(const bf16x8*)&hst[16 + lr][ks * 32 + lk * 8];
      #pragma unroll
      for (int ni = 0; ni < 8; ni++) {
        int col = wid * 128 + ni * 16 + lr;
        bf16x8 bv = *(const bf16x8*)(whhT + (size_t)col * 128 + ks * 32 + lk * 8);
        acc[0][ni] = __builtin_amdgcn_mfma_f32_16x16x32_bf16(af0, bv, acc[0][ni], 0, 0, 0);
        acc[1][ni] = __builtin_amdgcn_mfma_f32_16x16x32_bf16(af1, bv, acc[1][ni], 0, 0, 0);
      }
    }
    #pragma unroll
    for (int mi = 0; mi < 2; mi++)
      #pragma unroll
      for (int ni = 0; ni < 8; ni++)
        #pragma unroll
        for (int rr = 0; rr < 4; rr++)
          G[mi * 16 + lk * 4 + rr][wid * 128 + ni * 16 + lr] = acc[mi][ni][rr];
    __syncthreads();

    const float* ig = w_ih + a * 512;
    for (int e = tid; e < 32 * 128; e += 256) {
      int r = e >> 7, j = e & 127;
      float gi = G[r][j]       + ig[j]       + b_ih[j]       + b_hh[j];
      float gf = G[r][j + 128] + ig[j + 128] + b_ih[j + 128] + b_hh[j + 128];
      float gg = G[r][j + 256] + ig[j + 256] + b_ih[j + 256] + b_hh[j + 256];
      float go = G[r][j + 384] + ig[j + 384] + b_ih[j + 384] + b_hh[j + 384];
      float c = cst[r][j];
      float si = 1.f / (1.f + __expf(-gi));
      float sf = 1.f / (1.f + __expf(-gf));
      float so = 1.f / (1.f + __expf(-go));
      float cn = sf * c + si * tanhf(gg);
      float h = so * tanhf(cn);
      cst[r][j] = cn;
      unsigned short hb = f2b(h);
      hst[r][j] = hb;
      h_all[((size_t)(r0 + r) * 16 + a) * 128 + j] = hb;
    }
    __syncthreads();
  }
}

extern "C" void kernel_launch(void* const* d_in, const int* in_sizes, int n_in,
                              void* d_out, int out_size, void* d_ws, size_t ws_size,
                              hipStream_t stream) {
  const float* obs   = (const float*)d_in[0];
  const float* bb_w1 = (const float*)d_in[1];
  const float* bb_b1 = (const float*)d_in[2];
  const float* bb_w2 = (const float*)d_in[3];
  const float* bb_b2 = (const float*)d_in[4];
  const float* pol_w = (const float*)d_in[5];
  const float* pol_b = (const float*)d_in[6];
  const float* y_w   = (const float*)d_in[7];
  const float* y_b   = (const float*)d_in[8];
  const float* ci_w  = (const float*)d_in[9];
  const float* ci_b  = (const float*)d_in[10];
  const float* w_ih  = (const float*)d_in[11];
  const float* w_hh  = (const float*)d_in[12];
  const float* b_ih  = (const float*)d_in[13];
  const float* b_hh  = (const float*)d_in[14];
  const float* z_w1  = (const float*)d_in[15];
  const float* z_b1  = (const float*)d_in[16];
  const float* z_w2  = (const float*)d_in[17];
  const float* z_b2  = (const float*)d_in[18];
  const float* q_w1  = (const float*)d_in[19];
  const float* q_b1  = (const float*)d_in[20];
  const float* q_w2  = (const float*)d_in[21];
  const float* q_b2  = (const float*)d_in[22];
  const float* a_w1  = (const float*)d_in[23];
  const float* a_b1  = (const float*)d_in[24];
  const float* a_w2  = (const float*)d_in[25];
  const float* a_b2  = (const float*)d_in[26];

  float* out = (float*)d_out;
  float* out_logits = out;                 // [8192][16]
  float* out_y      = out + 131072;        // [8192][600]
  float* out_z      = out + 5046272;       // [8192*16][600]  (rows = n*16+a)
  float* out_q      = out + 83689472;      // [8192*16][601]
  float* out_a      = out + 162463744;     // [8192*16][16]

  uint8_t* ws = (uint8_t*)d_ws;
  size_t off = 0;
  auto alc = [&](size_t bytes) -> void* {
    void* p = ws + off;
    off = (off + bytes + 255) & ~(size_t)255;
    return p;
  };
  unsigned short* W1T  = (unsigned short*)alc((size_t)512 * 1024 * 2);
  unsigned short* W2T  = (unsigned short*)alc((size_t)512 * 512 * 2);
  unsigned short* polT = (unsigned short*)alc((size_t)16 * 512 * 2);
  unsigned short* yT   = (unsigned short*)alc((size_t)600 * 512 * 2);
  unsigned short* ciT  = (unsigned short*)alc((size_t)128 * 512 * 2);
  unsigned short* whhT = (unsigned short*)alc((size_t)512 * 128 * 2);
  unsigned short* zw1T = (unsigned short*)alc((size_t)128 * 128 * 2);
  unsigned short* zw2T = (unsigned short*)alc((size_t)600 * 128 * 2);
  unsigned short* qw1T = (unsigned short*)alc((size_t)128 * 128 * 2);
  unsigned short* qw2T = (unsigned short*)alc((size_t)601 * 128 * 2);
  unsigned short* aw1T = (unsigned short*)alc((size_t)128 * 128 * 2);
  unsigned short* aw2T = (unsigned short*)alc((size_t)16 * 128 * 2);
  unsigned short* hid1 = (unsigned short*)alc((size_t)8192 * 512 * 2);
  unsigned short* emb  = (unsigned short*)alc((size_t)8192 * 512 * 2);
  float*          c0b  = (float*)alc((size_t)8192 * 128 * 4);
  unsigned short* hall = (unsigned short*)alc((size_t)8192 * 16 * 128 * 2);
  unsigned short* hh   = (unsigned short*)alc((size_t)131072 * 128 * 2);
  (void)ws_size; (void)in_sizes; (void)n_in; (void)out_size;

  dim3 B256(256);
  // weight transposes (f32 -> bf16 [N][K])
  tconv<<<dim3(16, 32), B256, 0, stream>>>(bb_w1, W1T, 1024, 512);
  tconv<<<dim3(16, 16), B256, 0, stream>>>(bb_w2, W2T, 512, 512);
  tconv<<<dim3(1, 16),  B256, 0, stream>>>(pol_w, polT, 512, 16);
  tconv<<<dim3(19, 16), B256, 0, stream>>>(y_w, yT, 512, 600);
  tconv<<<dim3(4, 16),  B256, 0, stream>>>(ci_w, ciT, 512, 128);
  tconv<<<dim3(16, 4),  B256, 0, stream>>>(w_hh, whhT, 128, 512);
  tconv<<<dim3(4, 4),   B256, 0, stream>>>(z_w1, zw1T, 128, 128);
  tconv<<<dim3(19, 4),  B256, 0, stream>>>(z_w2, zw2T, 128, 600);
  tconv<<<dim3(4, 4),   B256, 0, stream>>>(q_w1, qw1T, 128, 128);
  tconv<<<dim3(19, 4),  B256, 0, stream>>>(q_w2, qw2T, 128, 601);
  tconv<<<dim3(4, 4),   B256, 0, stream>>>(a_w1, aw1T, 128, 128);
  tconv<<<dim3(1, 4),   B256, 0, stream>>>(a_w2, aw2T, 128, 16);

  // backbone
  gemm_k<1, true,  true><<<dim3(8, 128), B256, 0, stream>>>(obs,  W1T, bb_b1, hid1, 8192, 512, 1024, 512);
  gemm_k<1, false, true><<<dim3(8, 128), B256, 0, stream>>>(hid1, W2T, bb_b2, emb,  8192, 512, 512,  512);
  // heads from emb
  gemm_k<0, false, false><<<dim3(1, 128),  B256, 0, stream>>>(emb, polT, pol_b, out_logits, 8192, 16,  512, 16);
  gemm_k<0, false, false><<<dim3(10, 128), B256, 0, stream>>>(emb, yT,   y_b,   out_y,      8192, 600, 512, 600);
  gemm_k<0, false, false><<<dim3(2, 128),  B256, 0, stream>>>(emb, ciT,  ci_b,  c0b,        8192, 128, 512, 128);
  // fused LSTM scan (h_all in [n][a][128] order)
  lstm_k<<<dim3(256), B256, 0, stream>>>(c0b, whhT, w_ih, b_ih, b_hh, hall);
  // head MLPs: hidden (relu, bf16) then output (f32 straight into d_out)
  gemm_k<1, false, true ><<<dim3(2, 2048),  B256, 0, stream>>>(hall, zw1T, z_b1, hh,    131072, 128, 128, 128);
  gemm_k<0, false, false><<<dim3(10, 2048), B256, 0, stream>>>(hh,   zw2T, z_b2, out_z, 131072, 600, 128, 600);
  gemm_k<1, false, true ><<<dim3(2, 2048),  B256, 0, stream>>>(hall, qw1T, q_b1, hh,    131072, 128, 128, 128);
  gemm_k<0, false, false><<<dim3(10, 2048), B256, 0, stream>>>(hh,   qw2T, q_b2, out_q, 131072, 601, 128, 601);
  gemm_k<1, false, true ><<<dim3(2, 2048),  B256, 0, stream>>>(hall, aw1T, a_b1, hh,    131072, 128, 128, 128);
  gemm_k<0, false, false><<<dim3(1, 2048),  B256, 0, stream>>>(hh,   aw2T, a_b2, out_a, 131072, 16,  128, 16);
}

// Round 2
// 523.151 us; speedup vs baseline: 1.1293x; 1.1293x over previous
//
#include <hip/hip_runtime.h>
#include <stdint.h>

typedef short bf16x8 __attribute__((ext_vector_type(8)));
typedef float f32x4 __attribute__((ext_vector_type(4)));

__device__ __forceinline__ unsigned short f2b(float f) {
  union { float f; unsigned u; } v; v.f = f;
  unsigned r = v.u + 0x7fffu + ((v.u >> 16) & 1u);
  return (unsigned short)(r >> 16);
}

// ---------------- fused transpose+convert: f32[R][C] -> bf16 out[C][R], 12 matrices ----------------
struct TD { const float* in; unsigned short* out; int R, C; };
struct TDs { TD d[12]; };

__global__ __launch_bounds__(256) void tconv_all(TDs ds) {
  TD t = ds.d[blockIdx.z];
  int c0 = blockIdx.x * 32, r0 = blockIdx.y * 32;
  if (c0 >= t.C || r0 >= t.R) return;
  __shared__ float tl[32][33];
  int tx = threadIdx.x & 31, ty = threadIdx.x >> 5;  // 32 x 8
  #pragma unroll
  for (int i = 0; i < 32; i += 8) {
    int r = r0 + ty + i, c = c0 + tx;
    tl[ty + i][tx] = (r < t.R && c < t.C) ? t.in[(size_t)r * t.C + c] : 0.f;
  }
  __syncthreads();
  #pragma unroll
  for (int i = 0; i < 32; i += 8) {
    int c = c0 + ty + i, r = r0 + tx;
    if (c < t.C && r < t.R) t.out[(size_t)c * t.R + r] = f2b(tl[tx][ty + i]);
  }
}

// ---------------- f32 -> bf16 flat convert ----------------
__global__ __launch_bounds__(256) void conv_k(const float* __restrict__ in,
                                              unsigned short* __restrict__ out, int n) {
  int i = (blockIdx.x * 256 + threadIdx.x) * 8;
  if (i >= n) return;
  float4 a = *(const float4*)(in + i);
  float4 b = *(const float4*)(in + i + 4);
  bf16x8 v;
  v[0] = (short)f2b(a.x); v[1] = (short)f2b(a.y); v[2] = (short)f2b(a.z); v[3] = (short)f2b(a.w);
  v[4] = (short)f2b(b.x); v[5] = (short)f2b(b.y); v[6] = (short)f2b(b.z); v[7] = (short)f2b(b.w);
  *(bf16x8*)(out + i) = v;
}

// ---------------- generic MFMA GEMM: C = act(A[M,K] @ BT[N,K]^T + bias) ----------------
template <int ACT, bool OBF16>
__global__ __launch_bounds__(256) void gemm_k(const unsigned short* __restrict__ A,
                                              const unsigned short* __restrict__ BT,
                                              const float* __restrict__ bias,
                                              void* __restrict__ Cp,
                                              int M, int N, int K, int ldC) {
  __shared__ unsigned short As[64][40];
  __shared__ unsigned short Bs[64][40];
  const int tid = threadIdx.x;
  const int n0 = blockIdx.x * 64;
  const int m0 = blockIdx.y * 64;
  const int wid = tid >> 6, lane = tid & 63;
  const int wm = (wid >> 1) * 32, wn = (wid & 1) * 32;
  const int lr = lane & 15, lk = lane >> 4;
  const int sr = tid >> 2, sc = (tid & 3) * 8;

  f32x4 acc[2][2] = {};

  for (int k0 = 0; k0 < K; k0 += 32) {
    *(bf16x8*)&As[sr][sc] = *(const bf16x8*)(A + (size_t)(m0 + sr) * K + k0 + sc);
    {
      int n = n0 + sr;
      bf16x8 v = {};
      if (n < N) v = *(const bf16x8*)(BT + (size_t)n * K + k0 + sc);
      *(bf16x8*)&Bs[sr][sc] = v;
    }
    __syncthreads();
    bf16x8 af[2], bfr[2];
    #pragma unroll
    for (int mi = 0; mi < 2; mi++) af[mi] = *(const bf16x8*)&As[wm + mi * 16 + lr][lk * 8];
    #pragma unroll
    for (int ni = 0; ni < 2; ni++) bfr[ni] = *(const bf16x8*)&Bs[wn + ni * 16 + lr][lk * 8];
    #pragma unroll
    for (int mi = 0; mi < 2; mi++)
      #pragma unroll
      for (int ni = 0; ni < 2; ni++)
        acc[mi][ni] = __builtin_amdgcn_mfma_f32_16x16x32_bf16(af[mi], bfr[ni], acc[mi][ni], 0, 0, 0);
    __syncthreads();
  }

  #pragma unroll
  for (int mi = 0; mi < 2; mi++)
    #pragma unroll
    for (int ni = 0; ni < 2; ni++) {
      int col = n0 + wn + ni * 16 + lr;
      if (col >= N) continue;
      float bv = bias[col];
      #pragma unroll
      for (int r = 0; r < 4; r++) {
        int row = m0 + wm + mi * 16 + lk * 4 + r;
        float v = acc[mi][ni][r] + bv;
        if (ACT == 1) v = fmaxf(v, 0.f);
        if (OBF16) ((unsigned short*)Cp)[(size_t)row * ldC + col] = f2b(v);
        else       ((float*)Cp)[(size_t)row * ldC + col] = v;
      }
    }
}

// ---------------- fused LSTM scan over 16 steps ----------------
__global__ __launch_bounds__(256) void lstm_k(const float* __restrict__ c0,
                                              const unsigned short* __restrict__ whhT,  // [512][128] bf16
                                              const float* __restrict__ w_ih,           // [16][512]
                                              const float* __restrict__ b_ih,
                                              const float* __restrict__ b_hh,
                                              unsigned short* __restrict__ h_all) {     // [8192][16][128] bf16
  __shared__ float G[32][516];
  __shared__ float cst[32][128];
  __shared__ unsigned short hst[32][136];
  const int tid = threadIdx.x, lane = tid & 63, wid = tid >> 6;
  const int r0 = blockIdx.x * 32;
  const int lr = lane & 15, lk = lane >> 4;

  for (int e = tid; e < 32 * 128; e += 256) {
    int r = e >> 7, j = e & 127;
    float c = c0[(size_t)(r0 + r) * 128 + j];
    cst[r][j] = c;
    hst[r][j] = f2b(tanhf(c));
  }
  __syncthreads();

  for (int a = 0; a < 16; a++) {
    f32x4 acc[2][8] = {};
    #pragma unroll
    for (int ks = 0; ks < 4; ks++) {
      bf16x8 af0 = *(const bf16x8*)&hst[lr][ks * 32 + lk * 8];
      bf16x8 af1 = *(const bf16x8*)&hst[16 + lr][ks * 32 + lk * 8];
      #pragma unroll
      for (int ni = 0; ni < 8; ni++) {
        int col = wid * 128 + ni * 16 + lr;
        bf16x8 bv = *(const bf16x8*)(whhT + (size_t)col * 128 + ks * 32 + lk * 8);
        acc[0][ni] = __builtin_amdgcn_mfma_f32_16x16x32_bf16(af0, bv, acc[0][ni], 0, 0, 0);
        acc[1][ni] = __builtin_amdgcn_mfma_f32_16x16x32_bf16(af1, bv, acc[1][ni], 0, 0, 0);
      }
    }
    #pragma unroll
    for (int mi = 0; mi < 2; mi++)
      #pragma unroll
      for (int ni = 0; ni < 8; ni++)
        #pragma unroll
        for (int rr = 0; rr < 4; rr++)
          G[mi * 16 + lk * 4 + rr][wid * 128 + ni * 16 + lr] = acc[mi][ni][rr];
    __syncthreads();

    const float* ig = w_ih + a * 512;
    for (int e = tid; e < 32 * 128; e += 256) {
      int r = e >> 7, j = e & 127;
      float gi = G[r][j]       + ig[j]       + b_ih[j]       + b_hh[j];
      float gf = G[r][j + 128] + ig[j + 128] + b_ih[j + 128] + b_hh[j + 128];
      float gg = G[r][j + 256] + ig[j + 256] + b_ih[j + 256] + b_hh[j + 256];
      float go = G[r][j + 384] + ig[j + 384] + b_ih[j + 384] + b_hh[j + 384];
      float c = cst[r][j];
      float si = 1.f / (1.f + __expf(-gi));
      float sf = 1.f / (1.f + __expf(-gf));
      float so = 1.f / (1.f + __expf(-go));
      float cn = sf * c + si * tanhf(gg);
      float h = so * tanhf(cn);
      cst[r][j] = cn;
      unsigned short hb = f2b(h);
      hst[r][j] = hb;
      h_all[((size_t)(r0 + r) * 16 + a) * 128 + j] = hb;
    }
    __syncthreads();
  }
}

// ---------------- fused head MLPs: hall -> (z, q, aux) ----------------
// Per block: 64 rows of hall staged in LDS; per head compute hidden (relu) in LDS,
// then output GEMM with weights streamed from L2, f32 stores straight to d_out.
__global__ __launch_bounds__(256) void heads_k(
    const unsigned short* __restrict__ hall,  // [131072][128]
    const unsigned short* __restrict__ zw1, const float* __restrict__ zb1,
    const unsigned short* __restrict__ zw2, const float* __restrict__ zb2,
    const unsigned short* __restrict__ qw1, const float* __restrict__ qb1,
    const unsigned short* __restrict__ qw2, const float* __restrict__ qb2,
    const unsigned short* __restrict__ aw1, const float* __restrict__ ab1,
    const unsigned short* __restrict__ aw2, const float* __restrict__ ab2,
    float* __restrict__ oz, float* __restrict__ oq, float* __restrict__ oa) {
  __shared__ unsigned short hs[64][136];
  __shared__ unsigned short hd[64][136];
  const int tid = threadIdx.x;
  const int r0 = blockIdx.x * 64;
  const int lane = tid & 63, wid = tid >> 6;
  const int lr = lane & 15, lk = lane >> 4;

  {
    int row = tid >> 2, cb = (tid & 3) * 8;
    #pragma unroll
    for (int it = 0; it < 4; it++) {
      int col = cb + it * 32;
      *(bf16x8*)&hs[row][col] = *(const bf16x8*)(hall + (size_t)(r0 + row) * 128 + col);
    }
  }
  __syncthreads();

  const unsigned short* W1[3] = {zw1, qw1, aw1};
  const float*          B1[3] = {zb1, qb1, ab1};
  const unsigned short* W2[3] = {zw2, qw2, aw2};
  const float*          B2[3] = {zb2, qb2, ab2};
  float*                OO[3] = {oz, oq, oa};
  const int             NN[3] = {600, 601, 16};

  #pragma unroll
  for (int hi = 0; hi < 3; hi++) {
    const unsigned short* w1 = W1[hi];
    const unsigned short* w2 = W2[hi];
    const float* b1 = B1[hi];
    const float* b2 = B2[hi];
    float* Oh = OO[hi];
    const int Nh = NN[hi];

    // ---- hidden: wave `wid` computes cols [wid*32, wid*32+32), all 64 rows ----
    {
      bf16x8 ha[4][4];
      #pragma unroll
      for (int mi = 0; mi < 4; mi++)
        #pragma unroll
        for (int ks = 0; ks < 4; ks++)
          ha[mi][ks] = *(const bf16x8*)&hs[mi * 16 + lr][ks * 32 + lk * 8];
      f32x4 hacc[4][2] = {};
      #pragma unroll
      for (int ks = 0; ks < 4; ks++)
        #pragma unroll
        for (int nj = 0; nj < 2; nj++) {
          int col = wid * 32 + nj * 16 + lr;
          bf16x8 bv = *(const bf16x8*)(w1 + (size_t)col * 128 + ks * 32 + lk * 8);
          #pragma unroll
          for (int mi = 0; mi < 4; mi++)
            hacc[mi][nj] = __builtin_amdgcn_mfma_f32_16x16x32_bf16(ha[mi][ks], bv, hacc[mi][nj], 0, 0, 0);
        }
      #pragma unroll
      for (int mi = 0; mi < 4; mi++)
        #pragma unroll
        for (int nj = 0; nj < 2; nj++) {
          int col = wid * 32 + nj * 16 + lr;
          float bb = b1[col];
          #pragma unroll
          for (int rr = 0; rr < 4; rr++) {
            int row = mi * 16 + lk * 4 + rr;
            hd[row][col] = f2b(fmaxf(hacc[mi][nj][rr] + bb, 0.f));
          }
        }
    }
    __syncthreads();

    // ---- output: N = Nh, wave handles a contiguous slice of n-frags ----
    {
      bf16x8 hda[4][4];
      #pragma unroll
      for (int mi = 0; mi < 4; mi++)
        #pragma unroll
        for (int ks = 0; ks < 4; ks++)
          hda[mi][ks] = *(const bf16x8*)&hd[mi * 16 + lr][ks * 32 + lk * 8];

      const int NF = (Nh + 15) >> 4;
      const int fpw = (NF + 3) >> 2;
      const int f0 = wid * fpw;
      const int f1 = min(NF, f0 + fpw);

      for (int f = f0; f < f1; f += 2) {
        f32x4 oacc[4][2] = {};
        #pragma unroll
        for (int ks = 0; ks < 4; ks++)
          #pragma unroll
          for (int nj = 0; nj < 2; nj++) {
            int nf = f + nj; nf = nf < f1 ? nf : f1 - 1;
            int col = nf * 16 + lr;
            int bc = col < Nh ? col : Nh - 1;
            bf16x8 bv = *(const bf16x8*)(w2 + (size_t)bc * 128 + ks * 32 + lk * 8);
            #pragma unroll
            for (int mi = 0; mi < 4; mi++)
              oacc[mi][nj] = __builtin_amdgcn_mfma_f32_16x16x32_bf16(hda[mi][ks], bv, oacc[mi][nj], 0, 0, 0);
          }
        #pragma unroll
        for (int nj = 0; nj < 2; nj++) {
          int nf = f + nj;
          if (nf >= f1) break;
          int col = nf * 16 + lr;
          if (col < Nh) {
            float bb = b2[col];
            #pragma unroll
            for (int mi = 0; mi < 4; mi++)
              #pragma unroll
              for (int rr = 0; rr < 4; rr++) {
                int row = r0 + mi * 16 + lk * 4 + rr;
                Oh[(size_t)row * Nh + col] = oacc[mi][nj][rr] + bb;
              }
          }
        }
      }
    }
    __syncthreads();
  }
}

extern "C" void kernel_launch(void* const* d_in, const int* in_sizes, int n_in,
                              void* d_out, int out_size, void* d_ws, size_t ws_size,
                              hipStream_t stream) {
  const float* obs   = (const float*)d_in[0];
  const float* bb_w1 = (const float*)d_in[1];
  const float* bb_b1 = (const float*)d_in[2];
  const float* bb_w2 = (const float*)d_in[3];
  const float* bb_b2 = (const float*)d_in[4];
  const float* pol_w = (const float*)d_in[5];
  const float* pol_b = (const float*)d_in[6];
  const float* y_w   = (const float*)d_in[7];
  const float* y_b   = (const float*)d_in[8];
  const float* ci_w  = (const float*)d_in[9];
  const float* ci_b  = (const float*)d_in[10];
  const float* w_ih  = (const float*)d_in[11];
  const float* w_hh  = (const float*)d_in[12];
  const float* b_ih  = (const float*)d_in[13];
  const float* b_hh  = (const float*)d_in[14];
  const float* z_w1  = (const float*)d_in[15];
  const float* z_b1  = (const float*)d_in[16];
  const float* z_w2  = (const float*)d_in[17];
  const float* z_b2  = (const float*)d_in[18];
  const float* q_w1  = (const float*)d_in[19];
  const float* q_b1  = (const float*)d_in[20];
  const float* q_w2  = (const float*)d_in[21];
  const float* q_b2  = (const float*)d_in[22];
  const float* a_w1  = (const float*)d_in[23];
  const float* a_b1  = (const float*)d_in[24];
  const float* a_w2  = (const float*)d_in[25];
  const float* a_b2  = (const float*)d_in[26];

  float* out = (float*)d_out;
  float* out_logits = out;                 // [8192][16]
  float* out_y      = out + 131072;        // [8192][600]
  float* out_z      = out + 5046272;       // [131072][600]
  float* out_q      = out + 83689472;      // [131072][601]
  float* out_a      = out + 162463744;     // [131072][16]

  uint8_t* ws = (uint8_t*)d_ws;
  size_t off = 0;
  auto alc = [&](size_t bytes) -> void* {
    void* p = ws + off;
    off = (off + bytes + 255) & ~(size_t)255;
    return p;
  };
  unsigned short* W1T  = (unsigned short*)alc((size_t)512 * 1024 * 2);
  unsigned short* W2T  = (unsigned short*)alc((size_t)512 * 512 * 2);
  unsigned short* polT = (unsigned short*)alc((size_t)16 * 512 * 2);
  unsigned short* yT   = (unsigned short*)alc((size_t)600 * 512 * 2);
  unsigned short* ciT  = (unsigned short*)alc((size_t)128 * 512 * 2);
  unsigned short* whhT = (unsigned short*)alc((size_t)512 * 128 * 2);
  unsigned short* zw1T = (unsigned short*)alc((size_t)128 * 128 * 2);
  unsigned short* zw2T = (unsigned short*)alc((size_t)600 * 128 * 2);
  unsigned short* qw1T = (unsigned short*)alc((size_t)128 * 128 * 2);
  unsigned short* qw2T = (unsigned short*)alc((size_t)601 * 128 * 2);
  unsigned short* aw1T = (unsigned short*)alc((size_t)128 * 128 * 2);
  unsigned short* aw2T = (unsigned short*)alc((size_t)16 * 128 * 2);
  unsigned short* obsb = (unsigned short*)alc((size_t)8192 * 1024 * 2);
  unsigned short* hid1 = (unsigned short*)alc((size_t)8192 * 512 * 2);
  unsigned short* emb  = (unsigned short*)alc((size_t)8192 * 512 * 2);
  float*          c0b  = (float*)alc((size_t)8192 * 128 * 4);
  unsigned short* hall = (unsigned short*)alc((size_t)8192 * 16 * 128 * 2);
  (void)ws_size; (void)in_sizes; (void)n_in; (void)out_size;

  dim3 B256(256);

  TDs td;
  td.d[0]  = {bb_w1, W1T, 1024, 512};
  td.d[1]  = {bb_w2, W2T, 512, 512};
  td.d[2]  = {pol_w, polT, 512, 16};
  td.d[3]  = {y_w,   yT,   512, 600};
  td.d[4]  = {ci_w,  ciT,  512, 128};
  td.d[5]  = {w_hh,  whhT, 128, 512};
  td.d[6]  = {z_w1,  zw1T, 128, 128};
  td.d[7]  = {z_w2,  zw2T, 128, 600};
  td.d[8]  = {q_w1,  qw1T, 128, 128};
  td.d[9]  = {q_w2,  qw2T, 128, 601};
  td.d[10] = {a_w1,  aw1T, 128, 128};
  td.d[11] = {a_w2,  aw2T, 128, 16};
  tconv_all<<<dim3(19, 32, 12), B256, 0, stream>>>(td);

  conv_k<<<dim3(4096), B256, 0, stream>>>(obs, obsb, 8192 * 1024);

  // backbone
  gemm_k<1, true><<<dim3(8, 128), B256, 0, stream>>>(obsb, W1T, bb_b1, hid1, 8192, 512, 1024, 512);
  gemm_k<1, true><<<dim3(8, 128), B256, 0, stream>>>(hid1, W2T, bb_b2, emb,  8192, 512, 512,  512);
  // heads from emb
  gemm_k<0, false><<<dim3(1, 128),  B256, 0, stream>>>(emb, polT, pol_b, out_logits, 8192, 16,  512, 16);
  gemm_k<0, false><<<dim3(10, 128), B256, 0, stream>>>(emb, yT,   y_b,   out_y,      8192, 600, 512, 600);
  gemm_k<0, false><<<dim3(2, 128),  B256, 0, stream>>>(emb, ciT,  ci_b,  c0b,        8192, 128, 512, 128);
  // fused LSTM scan
  lstm_k<<<dim3(256), B256, 0, stream>>>(c0b, whhT, w_ih, b_ih, b_hh, hall);
  // fused head MLPs
  heads_k<<<dim3(2048), B256, 0, stream>>>(hall,
                                           zw1T, z_b1, zw2T, z_b2,
                                           qw1T, q_b1, qw2T, q_b2,
                                           aw1T, a_b1, aw2T, a_b2,
                                           out_z, out_q, out_a);
}